// Round 4
// baseline (965.222 us; speedup 1.0000x reference)
//
#include <hip/hip_runtime.h>
#include <hip/hip_bf16.h>
#include <math.h>

namespace {
constexpr int CDIM   = 128;
constexpr int KCODES = 1024;
constexpr int HWSZ   = 4096;   // 64*64
constexpr int BATCH  = 16;
constexpr int NPOS   = BATCH * HWSZ;            // 65536
constexpr int TK     = 64;                      // codes per LDS tile
constexpr int NTILES = KCODES / TK;             // 16
constexpr size_t QELEMS   = (size_t)BATCH * CDIM * HWSZ;   // 8388608
constexpr size_t IDX_OFF  = QELEMS;                        // float32 elements
constexpr size_t LOSS_OFF = IDX_OFF + (size_t)NPOS;        // 8454144
constexpr size_t PERP_OFF = LOSS_OFF + 1;
// d_ws float-element offsets
constexpr int WS_C2   = 0;      // [0,1024)   float ||c_k||^2 (numpy-bit-exact)
constexpr int WS_HIST = 1024;   // [1024,2048) uint  usage counts
constexpr int WS_LOSS = 2048;   // [2048]     float sum ||z-q||^2
constexpr float INV_TOTAL = 1.0f / (float)QELEMS;
constexpr float INV_NPOS  = 1.0f / (float)NPOS;
}

// Bit-exact replica of numpy pairwise_sum for n=128 contiguous float32 applied
// to elementwise squares: 8 accumulator chains (stride 8), sequential within a
// chain, combined ((r0+r1)+(r2+r3))+((r4+r5)+(r6+r7)). __f*_rn forbids fma
// contraction (numpy multiplies into a temp, then adds — never fused).
__device__ __forceinline__ float np_sumsq_128(const float* v) {
    float r[8];
    #pragma unroll
    for (int j = 0; j < 8; ++j) r[j] = __fmul_rn(v[j], v[j]);
    #pragma unroll
    for (int i = 8; i < 128; i += 8) {
        #pragma unroll
        for (int j = 0; j < 8; ++j)
            r[j] = __fadd_rn(r[j], __fmul_rn(v[i + j], v[i + j]));
    }
    const float s01 = __fadd_rn(r[0], r[1]);
    const float s23 = __fadd_rn(r[2], r[3]);
    const float s45 = __fadd_rn(r[4], r[5]);
    const float s67 = __fadd_rn(r[6], r[7]);
    return __fadd_rn(__fadd_rn(s01, s23), __fadd_rn(s45, s67));
}

// ---- pass 0: codebook norms (numpy-bit-exact) + zero accumulators ----------
__global__ __launch_bounds__(256) void vq_prep(const float* __restrict__ cb,
                                               float* __restrict__ ws) {
    const int k = blockIdx.x * 256 + threadIdx.x;   // 0..1023
    const float* row = cb + (size_t)k * CDIM;
    float rr[CDIM];
    #pragma unroll
    for (int c = 0; c < CDIM; ++c) rr[c] = row[c];
    ws[WS_C2 + k] = np_sumsq_128(rr);
    ((unsigned int*)ws)[WS_HIST + k] = 0u;
    if (k == 0) ws[WS_LOSS] = 0.0f;
}

// ---- pass 1: argmin with numpy-replicated rounding chain -------------------
__global__ __launch_bounds__(256) void vq_main(const float* __restrict__ z,
                                               const float* __restrict__ cb,
                                               float* __restrict__ ws,
                                               float* __restrict__ out) {
    __shared__ __align__(16) float tile[TK * CDIM];   // 32 KB
    __shared__ unsigned int lhist[KCODES];            // 4 KB
    __shared__ float red[256];

    const int tid = threadIdx.x;
    const int n   = blockIdx.x * 256 + tid;
    const int b   = n >> 12;
    const int hw  = n & (HWSZ - 1);
    const float* zp  = z + (size_t)b * CDIM * HWSZ + hw;
    const float* c2g = ws + WS_C2;

    for (int i = tid; i < KCODES; i += 256) lhist[i] = 0u;

    float zr[CDIM];
    #pragma unroll
    for (int c = 0; c < CDIM; ++c) zr[c] = zp[(size_t)c * HWSZ];

    // z2 bit-identical to np.sum(z_flat*z_flat, axis=1)
    const float z2 = np_sumsq_128(zr);

    float best_d = INFINITY;
    int   best_k = 0;

    for (int t = 0; t < NTILES; ++t) {
        __syncthreads();
        const float4* src = (const float4*)(cb + (size_t)t * TK * CDIM);
        float4* dst = (float4*)tile;
        #pragma unroll
        for (int i = 0; i < (TK * CDIM / 4) / 256; ++i)
            dst[i * 256 + tid] = src[i * 256 + tid];
        __syncthreads();

        const int kbase = t * TK;
        for (int kk = 0; kk < TK; kk += 4) {
            const float4* p0 = (const float4*)(tile + (kk + 0) * CDIM);
            const float4* p1 = (const float4*)(tile + (kk + 1) * CDIM);
            const float4* p2 = (const float4*)(tile + (kk + 2) * CDIM);
            const float4* p3 = (const float4*)(tile + (kk + 3) * CDIM);
            // one sequential ascending-c fma chain per code (BLAS-like order)
            float a0 = 0.f, a1 = 0.f, a2 = 0.f, a3 = 0.f;
            #pragma unroll
            for (int q = 0; q < CDIM / 4; ++q) {
                const float4 v0 = p0[q], v1 = p1[q], v2 = p2[q], v3 = p3[q];
                const float zx = zr[4*q+0], zy = zr[4*q+1];
                const float zz = zr[4*q+2], zw = zr[4*q+3];
                a0 = fmaf(v0.x, zx, a0); a0 = fmaf(v0.y, zy, a0);
                a0 = fmaf(v0.z, zz, a0); a0 = fmaf(v0.w, zw, a0);
                a1 = fmaf(v1.x, zx, a1); a1 = fmaf(v1.y, zy, a1);
                a1 = fmaf(v1.z, zz, a1); a1 = fmaf(v1.w, zw, a1);
                a2 = fmaf(v2.x, zx, a2); a2 = fmaf(v2.y, zy, a2);
                a2 = fmaf(v2.z, zz, a2); a2 = fmaf(v2.w, zw, a2);
                a3 = fmaf(v3.x, zx, a3); a3 = fmaf(v3.y, zy, a3);
                a3 = fmaf(v3.z, zz, a3); a3 = fmaf(v3.w, zw, a3);
            }
            // d = fl(fl(z2 - 2*zc) + c2): fmaf(-2,a,z2) == fl(z2-2a) since 2a
            // exact; __fadd_rn forbids contraction of the final add.
            const float d0 = __fadd_rn(fmaf(-2.0f, a0, z2), c2g[kbase + kk + 0]);
            const float d1 = __fadd_rn(fmaf(-2.0f, a1, z2), c2g[kbase + kk + 1]);
            const float d2 = __fadd_rn(fmaf(-2.0f, a2, z2), c2g[kbase + kk + 2]);
            const float d3 = __fadd_rn(fmaf(-2.0f, a3, z2), c2g[kbase + kk + 3]);
            // strict < ascending k == np.argmin first-index tie-break
            if (d0 < best_d) { best_d = d0; best_k = kbase + kk + 0; }
            if (d1 < best_d) { best_d = d1; best_k = kbase + kk + 1; }
            if (d2 < best_d) { best_d = d2; best_k = kbase + kk + 2; }
            if (d3 < best_d) { best_d = d3; best_k = kbase + kk + 3; }
        }
    }

    // quantized output: fp32 gather of winning codebook row
    const float4* q4 = (const float4*)(cb + (size_t)best_k * CDIM);
    float* op = out + (size_t)b * CDIM * HWSZ + hw;
    #pragma unroll
    for (int q = 0; q < CDIM / 4; ++q) {
        const float4 v = q4[q];
        op[(size_t)(4 * q + 0) * HWSZ] = v.x;
        op[(size_t)(4 * q + 1) * HWSZ] = v.y;
        op[(size_t)(4 * q + 2) * HWSZ] = v.z;
        op[(size_t)(4 * q + 3) * HWSZ] = v.w;
    }

    // index output (fp32)
    out[IDX_OFF + (size_t)n] = (float)best_k;

    // loss: best_d == fl(||z-q||^2), ~128 magnitude, 2% slack
    atomicAdd(&lhist[best_k], 1u);
    red[tid] = best_d;
    __syncthreads();
    for (int s = 128; s > 0; s >>= 1) {
        if (tid < s) red[tid] += red[tid + s];
        __syncthreads();
    }
    if (tid == 0) atomicAdd(&ws[WS_LOSS], red[0]);

    unsigned int* ghist = (unsigned int*)ws + WS_HIST;
    for (int i = tid; i < KCODES; i += 256) {
        const unsigned int v = lhist[i];
        if (v) atomicAdd(&ghist[i], v);
    }
}

// ---- pass 2: scalars --------------------------------------------------------
__global__ __launch_bounds__(1024) void vq_final(const float* __restrict__ ws,
                                                 float* __restrict__ out) {
    __shared__ float red[1024];
    const int t = threadIdx.x;
    const unsigned int* hist = (const unsigned int*)ws + WS_HIST;
    const float p = (float)hist[t] * INV_NPOS;
    red[t] = p * logf(p + 1e-10f);
    __syncthreads();
    for (int s = 512; s > 0; s >>= 1) {
        if (t < s) red[t] += red[t + s];
        __syncthreads();
    }
    if (t == 0) {
        out[LOSS_OFF] = 1.25f * (ws[WS_LOSS] * INV_TOTAL);   // cb + 0.25*commit
        out[PERP_OFF] = expf(-red[0]);
    }
}

extern "C" void kernel_launch(void* const* d_in, const int* in_sizes, int n_in,
                              void* d_out, int out_size, void* d_ws, size_t ws_size,
                              hipStream_t stream) {
    const float* z  = (const float*)d_in[0];
    const float* cb = (const float*)d_in[1];
    float* out = (float*)d_out;
    float* ws  = (float*)d_ws;

    vq_prep <<<KCODES / 256, 256, 0, stream>>>(cb, ws);
    vq_main <<<NPOS / 256,   256, 0, stream>>>(z, cb, ws, out);
    vq_final<<<1,           1024, 0, stream>>>(ws, out);
}

// Round 5
// 961.827 us; speedup vs baseline: 1.0035x; 1.0035x over previous
//
#include <hip/hip_runtime.h>
#include <hip/hip_bf16.h>
#include <math.h>

namespace {
constexpr int CDIM   = 128;
constexpr int KCODES = 1024;
constexpr int HWSZ   = 4096;   // 64*64
constexpr int BATCH  = 16;
constexpr int NPOS   = BATCH * HWSZ;            // 65536
constexpr int TK     = 64;                      // codes per LDS tile
constexpr int NTILES = KCODES / TK;             // 16
constexpr size_t QELEMS   = (size_t)BATCH * CDIM * HWSZ;   // 8388608
constexpr size_t IDX_OFF  = QELEMS;                        // float32 elements
constexpr size_t LOSS_OFF = IDX_OFF + (size_t)NPOS;        // 8454144
constexpr size_t PERP_OFF = LOSS_OFF + 1;
// d_ws float-element offsets
constexpr int WS_C2   = 0;      // [0,1024)   float ||c_k||^2 (numpy-bit-exact)
constexpr int WS_HIST = 1024;   // [1024,2048) uint  usage counts
constexpr int WS_LOSS = 2048;   // [2048]     float sum ||z-q||^2
constexpr float INV_TOTAL = 1.0f / (float)QELEMS;
constexpr float INV_NPOS  = 1.0f / (float)NPOS;
}

// Bit-exact replica of numpy pairwise_sum for n=128 contiguous float32 applied
// to elementwise squares: 8 accumulator chains (stride 8), sequential within a
// chain, combined ((r0+r1)+(r2+r3))+((r4+r5)+(r6+r7)). __f*_rn forbids fma
// contraction (numpy multiplies into a temp, then adds — never fused).
__device__ __forceinline__ float np_sumsq_128(const float* v) {
    float r[8];
    #pragma unroll
    for (int j = 0; j < 8; ++j) r[j] = __fmul_rn(v[j], v[j]);
    #pragma unroll
    for (int i = 8; i < 128; i += 8) {
        #pragma unroll
        for (int j = 0; j < 8; ++j)
            r[j] = __fadd_rn(r[j], __fmul_rn(v[i + j], v[i + j]));
    }
    const float s01 = __fadd_rn(r[0], r[1]);
    const float s23 = __fadd_rn(r[2], r[3]);
    const float s45 = __fadd_rn(r[4], r[5]);
    const float s67 = __fadd_rn(r[6], r[7]);
    return __fadd_rn(__fadd_rn(s01, s23), __fadd_rn(s45, s67));
}

// ---- pass 0: codebook norms (numpy-bit-exact) + zero accumulators ----------
__global__ __launch_bounds__(256) void vq_prep(const float* __restrict__ cb,
                                               float* __restrict__ ws) {
    const int k = blockIdx.x * 256 + threadIdx.x;   // 0..1023
    const float* row = cb + (size_t)k * CDIM;
    float rr[CDIM];
    #pragma unroll
    for (int c = 0; c < CDIM; ++c) rr[c] = row[c];
    ws[WS_C2 + k] = np_sumsq_128(rr);
    ((unsigned int*)ws)[WS_HIST + k] = 0u;
    if (k == 0) ws[WS_LOSS] = 0.0f;
}

// ---- pass 1: argmin with numpy-replicated rounding chain -------------------
// launch_bounds(256,1): grid is 256 blocks == 1 block/CU regardless, so give
// the allocator the full 512-VGPR budget — zr[128] must stay in registers.
// (Round 4: VGPR_Count=88 -> compiler rematerialized zr as global loads in the
// inner loop -> VALUBusy 26%, 927 us.)
__global__ __launch_bounds__(256, 1) void vq_main(const float* __restrict__ z,
                                                  const float* __restrict__ cb,
                                                  float* __restrict__ ws,
                                                  float* __restrict__ out) {
    __shared__ __align__(16) float tile[TK * CDIM];   // 32 KB
    __shared__ unsigned int lhist[KCODES];            // 4 KB
    __shared__ float red[256];

    const int tid = threadIdx.x;
    const int n   = blockIdx.x * 256 + tid;
    const int b   = n >> 12;
    const int hw  = n & (HWSZ - 1);
    const float* zp  = z + (size_t)b * CDIM * HWSZ + hw;
    const float* c2g = ws + WS_C2;

    for (int i = tid; i < KCODES; i += 256) lhist[i] = 0u;

    float zr[CDIM];
    #pragma unroll
    for (int c = 0; c < CDIM; ++c) zr[c] = zp[(size_t)c * HWSZ];

    // z2 bit-identical to np.sum(z_flat*z_flat, axis=1)
    const float z2 = np_sumsq_128(zr);

    float best_d = INFINITY;
    int   best_k = 0;

    for (int t = 0; t < NTILES; ++t) {
        __syncthreads();
        const float4* src = (const float4*)(cb + (size_t)t * TK * CDIM);
        float4* dst = (float4*)tile;
        #pragma unroll
        for (int i = 0; i < (TK * CDIM / 4) / 256; ++i)
            dst[i * 256 + tid] = src[i * 256 + tid];
        __syncthreads();

        const int kbase = t * TK;
        for (int kk = 0; kk < TK; kk += 4) {
            const float4* p0 = (const float4*)(tile + (kk + 0) * CDIM);
            const float4* p1 = (const float4*)(tile + (kk + 1) * CDIM);
            const float4* p2 = (const float4*)(tile + (kk + 2) * CDIM);
            const float4* p3 = (const float4*)(tile + (kk + 3) * CDIM);
            // one sequential ascending-c fma chain per code (BLAS-like order)
            float a0 = 0.f, a1 = 0.f, a2 = 0.f, a3 = 0.f;
            #pragma unroll
            for (int q = 0; q < CDIM / 4; ++q) {
                const float4 v0 = p0[q], v1 = p1[q], v2 = p2[q], v3 = p3[q];
                const float zx = zr[4*q+0], zy = zr[4*q+1];
                const float zz = zr[4*q+2], zw = zr[4*q+3];
                a0 = fmaf(v0.x, zx, a0); a0 = fmaf(v0.y, zy, a0);
                a0 = fmaf(v0.z, zz, a0); a0 = fmaf(v0.w, zw, a0);
                a1 = fmaf(v1.x, zx, a1); a1 = fmaf(v1.y, zy, a1);
                a1 = fmaf(v1.z, zz, a1); a1 = fmaf(v1.w, zw, a1);
                a2 = fmaf(v2.x, zx, a2); a2 = fmaf(v2.y, zy, a2);
                a2 = fmaf(v2.z, zz, a2); a2 = fmaf(v2.w, zw, a2);
                a3 = fmaf(v3.x, zx, a3); a3 = fmaf(v3.y, zy, a3);
                a3 = fmaf(v3.z, zz, a3); a3 = fmaf(v3.w, zw, a3);
            }
            // d = fl(fl(z2 - 2*zc) + c2): fmaf(-2,a,z2) == fl(z2-2a) since 2a
            // exact; __fadd_rn forbids contraction of the final add.
            const float d0 = __fadd_rn(fmaf(-2.0f, a0, z2), c2g[kbase + kk + 0]);
            const float d1 = __fadd_rn(fmaf(-2.0f, a1, z2), c2g[kbase + kk + 1]);
            const float d2 = __fadd_rn(fmaf(-2.0f, a2, z2), c2g[kbase + kk + 2]);
            const float d3 = __fadd_rn(fmaf(-2.0f, a3, z2), c2g[kbase + kk + 3]);
            // strict < ascending k == np.argmin first-index tie-break
            if (d0 < best_d) { best_d = d0; best_k = kbase + kk + 0; }
            if (d1 < best_d) { best_d = d1; best_k = kbase + kk + 1; }
            if (d2 < best_d) { best_d = d2; best_k = kbase + kk + 2; }
            if (d3 < best_d) { best_d = d3; best_k = kbase + kk + 3; }
        }
    }

    // quantized output: fp32 gather of winning codebook row
    const float4* q4 = (const float4*)(cb + (size_t)best_k * CDIM);
    float* op = out + (size_t)b * CDIM * HWSZ + hw;
    #pragma unroll
    for (int q = 0; q < CDIM / 4; ++q) {
        const float4 v = q4[q];
        op[(size_t)(4 * q + 0) * HWSZ] = v.x;
        op[(size_t)(4 * q + 1) * HWSZ] = v.y;
        op[(size_t)(4 * q + 2) * HWSZ] = v.z;
        op[(size_t)(4 * q + 3) * HWSZ] = v.w;
    }

    // index output (fp32)
    out[IDX_OFF + (size_t)n] = (float)best_k;

    // loss: best_d == fl(||z-q||^2), ~128 magnitude, 2% slack
    atomicAdd(&lhist[best_k], 1u);
    red[tid] = best_d;
    __syncthreads();
    for (int s = 128; s > 0; s >>= 1) {
        if (tid < s) red[tid] += red[tid + s];
        __syncthreads();
    }
    if (tid == 0) atomicAdd(&ws[WS_LOSS], red[0]);

    unsigned int* ghist = (unsigned int*)ws + WS_HIST;
    for (int i = tid; i < KCODES; i += 256) {
        const unsigned int v = lhist[i];
        if (v) atomicAdd(&ghist[i], v);
    }
}

// ---- pass 2: scalars --------------------------------------------------------
__global__ __launch_bounds__(1024) void vq_final(const float* __restrict__ ws,
                                                 float* __restrict__ out) {
    __shared__ float red[1024];
    const int t = threadIdx.x;
    const unsigned int* hist = (const unsigned int*)ws + WS_HIST;
    const float p = (float)hist[t] * INV_NPOS;
    red[t] = p * logf(p + 1e-10f);
    __syncthreads();
    for (int s = 512; s > 0; s >>= 1) {
        if (t < s) red[t] += red[t + s];
        __syncthreads();
    }
    if (t == 0) {
        out[LOSS_OFF] = 1.25f * (ws[WS_LOSS] * INV_TOTAL);   // cb + 0.25*commit
        out[PERP_OFF] = expf(-red[0]);
    }
}

extern "C" void kernel_launch(void* const* d_in, const int* in_sizes, int n_in,
                              void* d_out, int out_size, void* d_ws, size_t ws_size,
                              hipStream_t stream) {
    const float* z  = (const float*)d_in[0];
    const float* cb = (const float*)d_in[1];
    float* out = (float*)d_out;
    float* ws  = (float*)d_ws;

    vq_prep <<<KCODES / 256, 256, 0, stream>>>(cb, ws);
    vq_main <<<NPOS / 256,   256, 0, stream>>>(z, cb, ws, out);
    vq_final<<<1,           1024, 0, stream>>>(ws, out);
}